// Round 6
// baseline (1480.926 us; speedup 1.0000x reference)
//
#include <hip/hip_runtime.h>
#include <math.h>

#define MDIM   4096
#define NSTEPS 199
#define NBLK   256     // one block per CU
#define NTHR   1024    // 16 waves; wave w owns row bid*16+w
#define B1C    0.9f
#define B2C    0.999f
#define EPSC   1e-8f

// Native ext-vector so "+v" asm constraints bind a 4-VGPR tuple cleanly.
typedef float f4 __attribute__((ext_vector_type(4)));

// ---------------------------------------------------------------------------
// Prep: Qs[i][j] = 0.5*(va[i][j] + va[j][i]), LDS-tiled transpose (validated R1).
// ---------------------------------------------------------------------------
__global__ void prep_qs(const float* __restrict__ va, float* __restrict__ Qs) {
    __shared__ float tile[32][33];
    const int j0 = blockIdx.x * 32;
    const int i0 = blockIdx.y * 32;
    const int tx = threadIdx.x, ty = threadIdx.y;

    for (int k = 0; k < 32; k += 8)
        tile[ty + k][tx] = va[(size_t)(j0 + ty + k) * MDIM + i0 + tx];
    __syncthreads();
    for (int k = 0; k < 32; k += 8) {
        int i = i0 + ty + k;
        float a = va[(size_t)i * MDIM + j0 + tx];
        float b = tile[tx][ty + k];          // va[j][i]
        Qs[(size_t)i * MDIM + j0 + tx] = 0.5f * (a + b);
    }
}

// ---------------------------------------------------------------------------
// Init: u0 = 1 - mean; zero the barrier flag array.
// ---------------------------------------------------------------------------
__global__ void init_state(const float* __restrict__ mean,
                           float* __restrict__ u0,
                           int* __restrict__ flags, int nflags) {
    int i = blockIdx.x * blockDim.x + threadIdx.x;
    if (i < MDIM)   u0[i] = 1.0f - mean[i];
    if (i < nflags) flags[i] = 0;
}

// ---------------------------------------------------------------------------
// Persistent cooperative kernel, fp32 end-to-end.
// Wave w of block b owns row r=16b+w; its Q row lives in 64 VGPRs/lane,
// pinned by a loop-carried empty asm.
// R4 lesson: default occupancy target caps VGPRs at 64 -> pin spills.
// R5 lesson: __launch_bounds__(.,4) only sets an upper bound on VGPRs;
// the allocator still TARGETS 8 waves/EU and spills anyway.
// Fix: amdgpu_waves_per_eu(4,4) sets min=max=4 waves/EU -> the allocator's
// budget itself becomes 128 VGPRs/wave.
// ---------------------------------------------------------------------------
__global__ __launch_bounds__(NTHR)
__attribute__((amdgpu_waves_per_eu(4, 4)))
void adam_persist(
        const float* __restrict__ Qs,
        float* u0, float* u1,
        const float* __restrict__ mean,
        float* __restrict__ w_out,
        int* __restrict__ flags) {
    __shared__ float su[MDIM];
    f4* su4 = (f4*)su;

    const int tid  = threadIdx.x;
    const int bid  = blockIdx.x;
    const int wave = tid >> 6;
    const int lane = tid & 63;
    const int row  = bid * 16 + wave;

    // ---- one-time: Q row -> registers (64 VGPRs/lane) ----
    f4 qreg[16];
    const f4* qrow4 = (const f4*)(Qs + (size_t)row * MDIM);
#pragma unroll
    for (int it = 0; it < 16; ++it) qreg[it] = qrow4[lane + 64 * it];

    float m = 0.0f, v = 0.0f, b1p = 1.0f, b2p = 1.0f, unew = 0.0f;

    for (int t = 1; t <= NSTEPS; ++t) {
        // Loop-carried liveness pin: compiler must keep qreg in VGPRs
        // (cannot rematerialize from Qs since the asm "may modify" it).
#pragma unroll
        for (int it = 0; it < 16; ++it)
            asm volatile("" : "+v"(qreg[it]));

        const float* uin  = (t & 1) ? u0 : u1;   // t=1 reads u0
        float*       uout = (t & 1) ? u1 : u0;

        // ---- stage u into LDS (agent-coherent loads bypass stale L2) ----
#pragma unroll
        for (int k = 0; k < 4; ++k) {
            int idx = tid + NTHR * k;
            su[idx] = __hip_atomic_load(uin + idx, __ATOMIC_RELAXED,
                                        __HIP_MEMORY_SCOPE_AGENT);
        }
        __syncthreads();

        // ---- row dot from registers ----
        float acc = 0.0f;
#pragma unroll
        for (int it = 0; it < 16; ++it) {
            f4 q = qreg[it];
            f4 u = su4[lane + 64 * it];
            acc += q.x * u.x + q.y * u.y + q.z * u.z + q.w * u.w;
        }
#pragma unroll
        for (int off = 32; off > 0; off >>= 1) acc += __shfl_xor(acc, off);
        const float g = acc;

        // ---- Adam update (state in registers, replicated across lanes) ----
        b1p *= B1C;
        b2p *= B2C;
        m = B1C * m + (1.0f - B1C) * g;
        v = B2C * v + (1.0f - B2C) * g * g;
        const float denom = sqrtf(v) / sqrtf(1.0f - b2p) + EPSC;
        unew = su[row] - (0.1f / (1.0f - b1p)) * m / denom;

        if (lane == 0)
            __hip_atomic_store(uout + row, unew, __ATOMIC_RELAXED,
                               __HIP_MEMORY_SCOPE_AGENT);
        // syncthreads drains the store (s_waitcnt vmcnt(0) before s_barrier)
        // -> release ordering for the flag below.
        __syncthreads();

        if (tid == 0)
            __hip_atomic_store(flags + t * NBLK + bid, 1, __ATOMIC_RELAXED,
                               __HIP_MEMORY_SCOPE_AGENT);

        // ---- grid barrier: wave 0 polls all 256 per-block flags ----
        if (tid < 64) {
            const int* f = flags + t * NBLK + 4 * tid;
            int spin = 0;
            for (;;) {
                int s0 = __hip_atomic_load(f + 0, __ATOMIC_RELAXED, __HIP_MEMORY_SCOPE_AGENT);
                int s1 = __hip_atomic_load(f + 1, __ATOMIC_RELAXED, __HIP_MEMORY_SCOPE_AGENT);
                int s2 = __hip_atomic_load(f + 2, __ATOMIC_RELAXED, __HIP_MEMORY_SCOPE_AGENT);
                int s3 = __hip_atomic_load(f + 3, __ATOMIC_RELAXED, __HIP_MEMORY_SCOPE_AGENT);
                if ((s0 & s1 & s2 & s3) != 0) break;
                if (++spin > (1 << 25)) break;   // fail visibly, never hang
            }
        }
        __syncthreads();
    }

    if (lane == 0) w_out[row] = unew + mean[row];
}

extern "C" void kernel_launch(void* const* d_in, const int* in_sizes, int n_in,
                              void* d_out, int out_size, void* d_ws, size_t ws_size,
                              hipStream_t stream) {
    const float* mean = (const float*)d_in[0];   // (4096,)
    const float* va   = (const float*)d_in[1];   // (4096,4096)
    float* w_out = (float*)d_out;                // (4096,)

    float* ws = (float*)d_ws;
    float* Qs  = ws;                              // 64 MB
    float* u0  = ws + (size_t)MDIM * MDIM;        // 16 KB
    float* u1  = u0 + MDIM;                       // 16 KB
    int*   flg = (int*)(u1 + MDIM);               // (NSTEPS+1)*256 ints

    const int nflags = (NSTEPS + 1) * NBLK;

    prep_qs<<<dim3(MDIM / 32, MDIM / 32), dim3(32, 8), 0, stream>>>(va, Qs);
    init_state<<<(nflags + 255) / 256, 256, 0, stream>>>(mean, u0, flg, nflags);

    void* args[] = { (void*)&Qs, (void*)&u0, (void*)&u1,
                     (void*)&mean, (void*)&w_out, (void*)&flg };
    hipLaunchCooperativeKernel((const void*)adam_persist,
                               dim3(NBLK), dim3(NTHR), args, 0, stream);
}

// Round 8
// 1267.937 us; speedup vs baseline: 1.1680x; 1.1680x over previous
//
#include <hip/hip_runtime.h>
#include <math.h>

#define MDIM   4096
#define NSTEPS 199
#define B1C    0.9f
#define B2C    0.999f
#define EPSC   1e-8f

// Primary (register-resident Q): 512 blocks x 512 threads, 2 blocks/CU.
#define NBLK_A 512
#define NTHR_A 512
// Fallback (R3-verbatim, L3-streaming): 256 blocks x 1024 threads.
#define NBLK_B 256
#define NTHR_B 1024

typedef float f4 __attribute__((ext_vector_type(4)));

// ---------------------------------------------------------------------------
// Prep: Qs[i][j] = 0.5*(va[i][j] + va[j][i]), LDS-tiled transpose (validated R1).
// ---------------------------------------------------------------------------
__global__ void prep_qs(const float* __restrict__ va, float* __restrict__ Qs) {
    __shared__ float tile[32][33];
    const int j0 = blockIdx.x * 32;
    const int i0 = blockIdx.y * 32;
    const int tx = threadIdx.x, ty = threadIdx.y;

    for (int k = 0; k < 32; k += 8)
        tile[ty + k][tx] = va[(size_t)(j0 + ty + k) * MDIM + i0 + tx];
    __syncthreads();
    for (int k = 0; k < 32; k += 8) {
        int i = i0 + ty + k;
        float a = va[(size_t)i * MDIM + j0 + tx];
        float b = tile[tx][ty + k];          // va[j][i]
        Qs[(size_t)i * MDIM + j0 + tx] = 0.5f * (a + b);
    }
}

// ---------------------------------------------------------------------------
// Init: u0 = 1 - mean; zero BOTH barrier flag arrays.
// ---------------------------------------------------------------------------
__global__ void init_state(const float* __restrict__ mean,
                           float* __restrict__ u0,
                           int* __restrict__ flags, int nflags) {
    int i = blockIdx.x * blockDim.x + threadIdx.x;
    if (i < MDIM)   u0[i] = 1.0f - mean[i];
    if (i < nflags) flags[i] = 0;
}

// ---------------------------------------------------------------------------
// PRIMARY: 512x512, 60 KB static LDS -> compile-time occupancy 2 blocks/CU
// -> VGPR budget 128 -> qreg (64 VGPR) + overhead (~50) fits, pin holds.
// R7 lesson: exact-64KB LDS + coop launch failed co-residency; now 60 KB,
// plain launch (host gates on the occupancy query), dead-man timeout.
// Wave w of block b owns row 8b+w. Per-row math identical to R3.
// ---------------------------------------------------------------------------
__global__ __launch_bounds__(NTHR_A) void adam_persist_hi(
        const float* __restrict__ Qs,
        float* u0, float* u1,
        const float* __restrict__ mean,
        float* __restrict__ w_out,
        int* __restrict__ flags) {
    __shared__ float su[MDIM];          // 16 KB
    __shared__ float lds_pad[11264];    // 44 KB pad -> 60 KB total static LDS
    f4* su4 = (f4*)su;
    volatile int* s_dead = (volatile int*)lds_pad;   // pad[0] doubles as dead-flag

    const int tid  = threadIdx.x;
    const int bid  = blockIdx.x;
    const int wave = tid >> 6;
    const int lane = tid & 63;
    const int row  = bid * 8 + wave;

    // Keep the pad alive; also zeroes s_dead (pad[0]).
    volatile float* vp = lds_pad;
    vp[tid] = 0.0f;

    // ---- one-time: Q row -> registers (64 VGPRs/lane) ----
    f4 qreg[16];
    const f4* qrow4 = (const f4*)(Qs + (size_t)row * MDIM);
#pragma unroll
    for (int it = 0; it < 16; ++it) qreg[it] = qrow4[lane + 64 * it];

    float m = 0.0f, v = 0.0f, b1p = 1.0f, b2p = 1.0f, unew = 0.0f;

    for (int t = 1; t <= NSTEPS; ++t) {
        // Loop-carried liveness pin.
#pragma unroll
        for (int it = 0; it < 16; ++it)
            asm volatile("" : "+v"(qreg[it]));

        const float* uin  = (t & 1) ? u0 : u1;
        float*       uout = (t & 1) ? u1 : u0;

        // ---- stage u into LDS (agent-coherent loads) ----
#pragma unroll
        for (int k = 0; k < 8; ++k) {
            int idx = tid + NTHR_A * k;
            su[idx] = __hip_atomic_load(uin + idx, __ATOMIC_RELAXED,
                                        __HIP_MEMORY_SCOPE_AGENT);
        }
        __syncthreads();

        // ---- row dot from registers (same op order as R3) ----
        float acc = 0.0f;
#pragma unroll
        for (int it = 0; it < 16; ++it) {
            f4 q = qreg[it];
            f4 u = su4[lane + 64 * it];
            acc += q.x * u.x + q.y * u.y + q.z * u.z + q.w * u.w;
        }
#pragma unroll
        for (int off = 32; off > 0; off >>= 1) acc += __shfl_xor(acc, off);
        const float g = acc;

        b1p *= B1C;
        b2p *= B2C;
        m = B1C * m + (1.0f - B1C) * g;
        v = B2C * v + (1.0f - B2C) * g * g;
        const float denom = sqrtf(v) / sqrtf(1.0f - b2p) + EPSC;
        unew = su[row] - (0.1f / (1.0f - b1p)) * m / denom;

        if (lane == 0)
            __hip_atomic_store(uout + row, unew, __ATOMIC_RELAXED,
                               __HIP_MEMORY_SCOPE_AGENT);
        __syncthreads();   // drains store before flag (release ordering)

        if (tid == 0)
            __hip_atomic_store(flags + t * NBLK_A + bid, 1, __ATOMIC_RELAXED,
                               __HIP_MEMORY_SCOPE_AGENT);

        // ---- grid barrier: wave 0 polls 512 flags; dead-man on timeout ----
        if (tid < 64) {
            if (s_dead[0] == 0) {
                const int* f = flags + t * NBLK_A + 8 * tid;
                int spin = 0;
                for (;;) {
                    int all = 1;
#pragma unroll
                    for (int k = 0; k < 8; ++k)
                        all &= __hip_atomic_load(f + k, __ATOMIC_RELAXED,
                                                 __HIP_MEMORY_SCOPE_AGENT);
                    if (all) break;
                    if (++spin > (1 << 20)) { s_dead[0] = 1; break; }
                }
            }
        }
        __syncthreads();
    }

    if (lane == 0) w_out[row] = unew + mean[row];
}

// ---------------------------------------------------------------------------
// FALLBACK: R3-verbatim (passed @ 1048 us). 256x1024, L3-streamed Q rows.
// ---------------------------------------------------------------------------
__global__ __launch_bounds__(NTHR_B) void adam_persist_fb(
        const float* __restrict__ Qs,
        float* u0, float* u1,
        const float* __restrict__ mean,
        float* __restrict__ w_out,
        int* __restrict__ flags) {
    __shared__ float su[MDIM];
    f4* su4 = (f4*)su;

    const int tid  = threadIdx.x;
    const int bid  = blockIdx.x;
    const int wave = tid >> 6;
    const int lane = tid & 63;
    const int row  = bid * 16 + wave;

    f4 qreg[16];
    const f4* qrow4 = (const f4*)(Qs + (size_t)row * MDIM);
#pragma unroll
    for (int it = 0; it < 16; ++it) qreg[it] = qrow4[lane + 64 * it];

    float m = 0.0f, v = 0.0f, b1p = 1.0f, b2p = 1.0f, unew = 0.0f;

    for (int t = 1; t <= NSTEPS; ++t) {
        const float* uin  = (t & 1) ? u0 : u1;
        float*       uout = (t & 1) ? u1 : u0;

#pragma unroll
        for (int k = 0; k < 4; ++k) {
            int idx = tid + NTHR_B * k;
            su[idx] = __hip_atomic_load(uin + idx, __ATOMIC_RELAXED,
                                        __HIP_MEMORY_SCOPE_AGENT);
        }
        __syncthreads();

        float acc = 0.0f;
#pragma unroll
        for (int it = 0; it < 16; ++it) {
            f4 q = qreg[it];
            f4 u = su4[lane + 64 * it];
            acc += q.x * u.x + q.y * u.y + q.z * u.z + q.w * u.w;
        }
#pragma unroll
        for (int off = 32; off > 0; off >>= 1) acc += __shfl_xor(acc, off);
        const float g = acc;

        b1p *= B1C;
        b2p *= B2C;
        m = B1C * m + (1.0f - B1C) * g;
        v = B2C * v + (1.0f - B2C) * g * g;
        const float denom = sqrtf(v) / sqrtf(1.0f - b2p) + EPSC;
        unew = su[row] - (0.1f / (1.0f - b1p)) * m / denom;

        if (lane == 0)
            __hip_atomic_store(uout + row, unew, __ATOMIC_RELAXED,
                               __HIP_MEMORY_SCOPE_AGENT);
        __syncthreads();

        if (tid == 0)
            __hip_atomic_store(flags + t * NBLK_B + bid, 1, __ATOMIC_RELAXED,
                               __HIP_MEMORY_SCOPE_AGENT);

        if (tid < 64) {
            const int* f = flags + t * NBLK_B + 4 * tid;
            int spin = 0;
            for (;;) {
                int s0 = __hip_atomic_load(f + 0, __ATOMIC_RELAXED, __HIP_MEMORY_SCOPE_AGENT);
                int s1 = __hip_atomic_load(f + 1, __ATOMIC_RELAXED, __HIP_MEMORY_SCOPE_AGENT);
                int s2 = __hip_atomic_load(f + 2, __ATOMIC_RELAXED, __HIP_MEMORY_SCOPE_AGENT);
                int s3 = __hip_atomic_load(f + 3, __ATOMIC_RELAXED, __HIP_MEMORY_SCOPE_AGENT);
                if ((s0 & s1 & s2 & s3) != 0) break;
                if (++spin > (1 << 25)) break;
            }
        }
        __syncthreads();
    }

    if (lane == 0) w_out[row] = unew + mean[row];
}

extern "C" void kernel_launch(void* const* d_in, const int* in_sizes, int n_in,
                              void* d_out, int out_size, void* d_ws, size_t ws_size,
                              hipStream_t stream) {
    const float* mean = (const float*)d_in[0];   // (4096,)
    const float* va   = (const float*)d_in[1];   // (4096,4096)
    float* w_out = (float*)d_out;                // (4096,)

    float* ws = (float*)d_ws;
    float* Qs   = ws;                              // 64 MB
    float* u0   = ws + (size_t)MDIM * MDIM;        // 16 KB
    float* u1   = u0 + MDIM;                       // 16 KB
    int*   flgA = (int*)(u1 + MDIM);               // (NSTEPS+1)*512 ints
    int*   flgB = flgA + (NSTEPS + 1) * NBLK_A;    // (NSTEPS+1)*256 ints

    const int nflags = (NSTEPS + 1) * (NBLK_A + NBLK_B);

    prep_qs<<<dim3(MDIM / 32, MDIM / 32), dim3(32, 8), 0, stream>>>(va, Qs);
    init_state<<<(nflags + 255) / 256, 256, 0, stream>>>(mean, u0, flgA, nflags);

    // Capture-safe, deterministic occupancy gate: primary kernel needs
    // 2 blocks/CU co-resident for its hand-rolled barrier.
    int occ = 0;
    hipError_t e = hipOccupancyMaxActiveBlocksPerMultiprocessor(
        &occ, (const void*)adam_persist_hi, NTHR_A, 0);

    if (e == hipSuccess && occ >= 2) {
        adam_persist_hi<<<NBLK_A, NTHR_A, 0, stream>>>(Qs, u0, u1, mean, w_out, flgA);
    } else {
        void* args[] = { (void*)&Qs, (void*)&u0, (void*)&u1,
                         (void*)&mean, (void*)&w_out, (void*)&flgB };
        hipLaunchCooperativeKernel((const void*)adam_persist_fb,
                                   dim3(NBLK_B), dim3(NTHR_B), args, 0, stream);
    }
}